// Round 6
// baseline (240.256 us; speedup 1.0000x reference)
//
#include <hip/hip_runtime.h>
#include <hip/hip_bf16.h>
#include <cmath>

// Problem constants (from reference)
#define NTOK 4096      // B*T
#define Dm   512
#define Hm   1024
#define Cm   32
#define Km   3
#define NEVm 50
#define NGm  6
#define NBANK 14       // 2 shared + 12 group banks
#define Em   4         // S+G
#define MAXMT 144      // worst-case 128-token m-tiles
#define MT2  (MAXMT * 2)   // 64-token sub-tiles

#define CVT_BLKS   1024
#define TRANS_BLKS 3584

typedef __bf16 bf16x8 __attribute__((ext_vector_type(8)));
typedef float  floatx4 __attribute__((ext_vector_type(4)));

__device__ __forceinline__ void async16(const __bf16* g, const __bf16* l) {
    __builtin_amdgcn_global_load_lds(
        (const __attribute__((address_space(1))) void*)g,
        (__attribute__((address_space(3))) void*)l, 16, 0, 0);
}

// ---------------------------------------------------------------- setup
// ONE dispatch: block 0 = bucket+tile-table; blocks 1..1024 = x->bf16 cvt;
// blocks 1025..4608 = all 4 weight transposes (fp32 [R][C] -> bf16 [C][R]).
__global__ __launch_bounds__(256) void k_setup(
    const float* __restrict__ x, const int* __restrict__ ids,
    const int* __restrict__ e2g,
    const float* __restrict__ Ws1, const float* __restrict__ Wg1,
    const float* __restrict__ Ws2, const float* __restrict__ Wg2,
    int* __restrict__ gids, int* __restrict__ counts, int* __restrict__ lists,
    int2* __restrict__ table, int* __restrict__ ntot,
    __bf16* __restrict__ xb, __bf16* __restrict__ W1t, __bf16* __restrict__ W2t)
{
    const int b = blockIdx.x;
    const int t = threadIdx.x;

    if (b == 0) {
        // ---- bucket tokens by group + build tile table
        __shared__ int lcnt[NGm];
        const int lane = t & 63;
        if (t < NGm) lcnt[t] = 0;
        __syncthreads();
        for (int n = t; n < NTOK; n += 256) {
            int id = ids[n];
            id = id < 0 ? 0 : (id > NEVm - 1 ? NEVm - 1 : id);
            int g = e2g[id];
            gids[n] = g;
            int pos = 0;
            #pragma unroll
            for (int gg = 0; gg < NGm; gg++) {
                unsigned long long m = __ballot(g == gg);
                if (g == gg) {
                    int leader = __ffsll((unsigned long long)m) - 1;
                    int base = 0;
                    if (lane == leader) base = atomicAdd(&lcnt[gg], (int)__popcll(m));
                    base = __shfl(base, leader, 64);
                    pos = base + (int)__popcll(m & ((1ull << lane) - 1));
                }
            }
            lists[g * NTOK + pos] = n;
        }
        __syncthreads();
        if (t < NGm) counts[t] = lcnt[t];
        if (t == 0) {
            int idx = 0;
            for (int bb = 0; bb < 2; bb++)
                for (int m0 = 0; m0 < NTOK; m0 += 128) table[idx++] = make_int2(bb, m0);
            for (int g = 0; g < NGm; g++) {
                int c = lcnt[g];
                for (int gg = 0; gg < 2; gg++) {
                    int bank = 2 + 2 * g + gg;
                    for (int m0 = 0; m0 < c; m0 += 128) table[idx++] = make_int2(bank, m0);
                }
            }
            *ntot = idx;
        }
        return;
    }

    if (b <= CVT_BLKS) {
        // ---- x fp32 -> bf16
        int i = ((b - 1) * 256 + t) * 8;
        float4 a = *(const float4*)(x + i);
        float4 c = *(const float4*)(x + i + 4);
        bf16x8 v;
        v[0] = (__bf16)a.x; v[1] = (__bf16)a.y; v[2] = (__bf16)a.z; v[3] = (__bf16)a.w;
        v[4] = (__bf16)c.x; v[5] = (__bf16)c.y; v[6] = (__bf16)c.z; v[7] = (__bf16)c.w;
        *(bf16x8*)(xb + i) = v;
        return;
    }

    // ---- weight transposes
    __shared__ float tile[64][65];
    int idx = b - 1 - CVT_BLKS;
    const float* in; __bf16* out; int C, cshift, tile_i;
    const size_t HD = (size_t)Hm * Dm;
    if (idx < 1792) {
        int bank = idx >> 7; tile_i = idx & 127;
        C = Hm; cshift = 4;
        in = (bank < 2) ? (Ws1 + (size_t)bank * HD) : (Wg1 + (size_t)(bank - 2) * HD);
        out = W1t + (size_t)bank * HD;
    } else {
        idx -= 1792;
        int bank = idx >> 7; tile_i = idx & 127;
        C = Dm; cshift = 3;
        in = (bank < 2) ? (Ws2 + (size_t)bank * HD) : (Wg2 + (size_t)(bank - 2) * HD);
        out = W2t + (size_t)bank * HD;
    }
    const int r0 = (tile_i >> cshift) * 64;
    const int c0 = (tile_i & ((1 << cshift) - 1)) * 64;
    const int R = (C == Hm) ? Dm : Hm;
    {
        int r = t >> 2, cs = (t & 3) * 16;
        const float4* src = (const float4*)(in + (size_t)(r0 + r) * C + c0 + cs);
        #pragma unroll
        for (int i = 0; i < 4; i++) {
            float4 v = src[i];
            tile[r][cs + i * 4 + 0] = v.x;
            tile[r][cs + i * 4 + 1] = v.y;
            tile[r][cs + i * 4 + 2] = v.z;
            tile[r][cs + i * 4 + 3] = v.w;
        }
    }
    __syncthreads();
    {
        int c = t >> 2, rs = (t & 3) * 16;
        __bf16* dst = out + (size_t)(c0 + c) * R + r0 + rs;
        bf16x8 v0, v1;
        #pragma unroll
        for (int i = 0; i < 8; i++) v0[i] = (__bf16)tile[rs + i][c];
        #pragma unroll
        for (int i = 0; i < 8; i++) v1[i] = (__bf16)tile[rs + 8 + i][c];
        *(bf16x8*)dst = v0;
        *(bf16x8*)(dst + 8) = v1;
    }
}

// ---------------------------------------------------------------- fused FFN GEMM
// BM=64, BN=128, BK=32, double-buffered LDS (24KB -> 6 blocks/CU), prefetch
// across barrier, pair-packed XOR swizzle (conflict-free b128 frag reads).
// n-major block order: nt = blockIdx.x / MT2 -> 288 consecutive blocks share
// one W n-strip (L2 reuse); mt2 = blockIdx.x % MT2 picks the 64-token subtile.
template<int KDIM, int NDIM, bool RELU>
__global__ __launch_bounds__(256, 6) void k_ffn(
    const __bf16* __restrict__ Abase, int AstrTok, int AeStr,
    const __bf16* __restrict__ Wt,
    const float* __restrict__ bsh, const float* __restrict__ bgr,
    const int* __restrict__ counts, const int* __restrict__ lists,
    const int2* __restrict__ table, const int* __restrict__ ntot,
    __bf16* __restrict__ Obase, int OstrTok, int OeStr)
{
    constexpr int KT = KDIM / 32;
    const int nt = blockIdx.x / MT2;
    const int mt2 = blockIdx.x % MT2;
    const int mt = mt2 >> 1, sub = mt2 & 1;
    if (mt >= *ntot) return;
    const int2 te = table[mt];
    const int bank = te.x;
    const int m0 = te.y + (sub << 6);
    const int cnt = (bank < 2) ? NTOK : counts[(bank - 2) >> 1];
    if (m0 >= cnt) return;
    const int n0 = nt * 128;
    const int e = (bank < 2) ? bank : 2 + ((bank - 2) & 1);

    __shared__ int tok_lds[64];
    __shared__ __align__(16) __bf16 A_lds[2][64 * 32];
    __shared__ __align__(16) __bf16 B_lds[2][128 * 32];

    const int t = threadIdx.x;
    if (t < 64) {
        int idx = m0 + t;
        int tok = -1;
        if (idx < cnt) tok = (bank < 2) ? idx : lists[((bank - 2) >> 1) * NTOK + idx];
        tok_lds[t] = tok;
    }
    __syncthreads();

    const int w = t >> 6, lane = t & 63;

    // staging addresses. slot S -> line l=S>>3 (128B), granule g8=S&7;
    // content granule s=g8^(l&7): row=2l+(s>>2), 16B k-granule gk=s&3.
    // A: 256 slots (1/thread). B: 512 slots (2/thread).
    const __bf16* aG;
    {
        int l = t >> 3, g8 = t & 7;
        int s = g8 ^ (l & 7);
        int row = 2 * l + (s >> 2), gk = s & 3;
        int tok = tok_lds[row]; if (tok < 0) tok = 0;
        aG = Abase + (size_t)tok * AstrTok + (size_t)e * AeStr + gk * 8;
    }
    const __bf16* bG[2];
    #pragma unroll
    for (int r2 = 0; r2 < 2; r2++) {
        int S = t + r2 * 256;
        int l = S >> 3, g8 = S & 7;
        int s = g8 ^ (l & 7);
        int row = 2 * l + (s >> 2), gk = s & 3;
        bG[r2] = Wt + (size_t)bank * NDIM * KDIM + (size_t)(n0 + row) * KDIM + gk * 8;
    }

    // fragment offsets: addr = l*64 + g8*8 elems; l=row>>1; g8=(half*4+quad)^(l&7)
    const int col = lane & 15, quad = lane >> 4;
    const int mh = (w >> 1) * 32, nh = (w & 1) * 64;
    const int c2 = col >> 1, half = col & 1;
    const int g8r = ((half << 2) + quad) ^ c2;
    int aoff[2], boff[4];
    #pragma unroll
    for (int f = 0; f < 2; f++)
        aoff[f] = ((mh >> 1) + f * 8 + c2) * 64 + g8r * 8;
    #pragma unroll
    for (int f = 0; f < 4; f++)
        boff[f] = ((nh >> 1) + f * 8 + c2) * 64 + g8r * 8;

    floatx4 acc[2][4] = {};

    // prologue: stage k-tile 0 into buf 0
    async16(aG, &A_lds[0][w * 512]);
    #pragma unroll
    for (int r2 = 0; r2 < 2; r2++) async16(bG[r2], &B_lds[0][w * 512 + r2 * 2048]);
    __syncthreads();

    #pragma unroll 2
    for (int kt = 0; kt < KT; kt++) {
        const int p = kt & 1, q = p ^ 1;
        if (kt + 1 < KT) {
            const int ko = (kt + 1) * 32;
            async16(aG + ko, &A_lds[q][w * 512]);
            #pragma unroll
            for (int r2 = 0; r2 < 2; r2++) async16(bG[r2] + ko, &B_lds[q][w * 512 + r2 * 2048]);
        }
        bf16x8 af[2], bv[4];
        #pragma unroll
        for (int f = 0; f < 2; f++) af[f] = *(const bf16x8*)&A_lds[p][aoff[f]];
        #pragma unroll
        for (int f = 0; f < 4; f++) bv[f] = *(const bf16x8*)&B_lds[p][boff[f]];
        #pragma unroll
        for (int mf = 0; mf < 2; mf++)
            #pragma unroll
            for (int nf = 0; nf < 4; nf++)
                acc[mf][nf] = __builtin_amdgcn_mfma_f32_16x16x32_bf16(
                    af[mf], bv[nf], acc[mf][nf], 0, 0, 0);
        __syncthreads();
    }

    const float* bp = (bank < 2) ? (bsh + (size_t)bank * NDIM)
                                 : (bgr + (size_t)(bank - 2) * NDIM);
    float bias[4];
    #pragma unroll
    for (int nf = 0; nf < 4; nf++) bias[nf] = bp[n0 + nh + nf * 16 + col];

    #pragma unroll
    for (int mf = 0; mf < 2; mf++) {
        #pragma unroll
        for (int r = 0; r < 4; r++) {
            int m = mh + mf * 16 + quad * 4 + r;
            int tok = tok_lds[m];
            if (tok >= 0) {
                __bf16* orow = Obase + (size_t)tok * OstrTok + (size_t)e * OeStr + n0 + nh + col;
                #pragma unroll
                for (int nf = 0; nf < 4; nf++) {
                    float v = acc[mf][nf][r] + bias[nf];
                    if (RELU) v = fmaxf(v, 0.0f);
                    orow[nf * 16] = (__bf16)v;
                }
            }
        }
    }
}

// ---------------------------------------------------------------- fused gate+combine
__global__ __launch_bounds__(256) void k_gc(
    const float* __restrict__ x, const float* __restrict__ cond_emb,
    const int* __restrict__ gids, const float* __restrict__ gW,
    const float* __restrict__ gb, const __bf16* __restrict__ eo,
    float* __restrict__ out)
{
    __shared__ float gwl[544 * 13];
    const int t = threadIdx.x;
    for (int i = t; i < 544 * 12; i += 256) {
        int f = i / 12, j = i - f * 12;
        gwl[f * 13 + j] = gW[((size_t)(j >> 2) * 544 + f) * 4 + (j & 3)];
    }
    __syncthreads();

    const int wave = t >> 6, lane = t & 63;
    const int tok = blockIdx.x * 4 + wave;
    const int gid = gids[tok];
    const float* xr = x + (size_t)tok * Dm;

    float a[12] = {};
    #pragma unroll
    for (int j = 0; j < 8; j++) {
        float xv = xr[j * 64 + lane];
        const float* base = &gwl[(j * 64 + lane) * 13];
        #pragma unroll
        for (int jj = 0; jj < 12; jj++) a[jj] += xv * base[jj];
    }
    if (lane < Cm) {
        float xv = cond_emb[gid * Cm + lane];
        const float* base = &gwl[(Dm + lane) * 13];
        #pragma unroll
        for (int jj = 0; jj < 12; jj++) a[jj] += xv * base[jj];
    }
    #pragma unroll
    for (int off = 1; off < 64; off <<= 1)
        #pragma unroll
        for (int jj = 0; jj < 12; jj++)
            a[jj] += __shfl_xor(a[jj], off, 64);

    float w[Km][Em];
    #pragma unroll
    for (int k = 0; k < Km; k++) {
        float v0 = a[k * 4 + 0] + gb[k * 4 + 0];
        float v1 = a[k * 4 + 1] + gb[k * 4 + 1];
        float v2 = a[k * 4 + 2] + gb[k * 4 + 2];
        float v3 = a[k * 4 + 3] + gb[k * 4 + 3];
        float m = fmaxf(fmaxf(v0, v1), fmaxf(v2, v3));
        float e0 = __expf(v0 - m), e1 = __expf(v1 - m), e2 = __expf(v2 - m), e3 = __expf(v3 - m);
        float inv = 1.0f / (e0 + e1 + e2 + e3);
        w[k][0] = e0 * inv; w[k][1] = e1 * inv; w[k][2] = e2 * inv; w[k][3] = e3 * inv;
    }

    const int d0 = lane * 8;
    const __bf16* ep = eo + (size_t)tok * Em * Dm;
    float o[Km][8] = {};
    #pragma unroll
    for (int e = 0; e < Em; e++) {
        bf16x8 v = *(const bf16x8*)(ep + (size_t)e * Dm + d0);
        float f[8];
        #pragma unroll
        for (int i = 0; i < 8; i++) f[i] = (float)v[i];
        #pragma unroll
        for (int k = 0; k < Km; k++)
            #pragma unroll
            for (int i = 0; i < 8; i++) o[k][i] += w[k][e] * f[i];
    }
    #pragma unroll
    for (int k = 0; k < Km; k++) {
        float* op = out + ((size_t)k * NTOK + tok) * Dm + d0;
        *(float4*)op = make_float4(o[k][0], o[k][1], o[k][2], o[k][3]);
        *(float4*)(op + 4) = make_float4(o[k][4], o[k][5], o[k][6], o[k][7]);
    }
}

// ---------------------------------------------------------------- launch

static inline size_t align256(size_t v) { return (v + 255) & ~(size_t)255; }

extern "C" void kernel_launch(void* const* d_in, const int* in_sizes, int n_in,
                              void* d_out, int out_size, void* d_ws, size_t ws_size,
                              hipStream_t stream) {
    const float* x        = (const float*)d_in[0];
    const int*   ids      = (const int*)d_in[1];
    const int*   e2g      = (const int*)d_in[2];
    const float* Ws1      = (const float*)d_in[3];
    const float* bs1      = (const float*)d_in[4];
    const float* Ws2      = (const float*)d_in[5];
    const float* bs2      = (const float*)d_in[6];
    const float* Wg1      = (const float*)d_in[7];
    const float* bg1      = (const float*)d_in[8];
    const float* Wg2      = (const float*)d_in[9];
    const float* bg2      = (const float*)d_in[10];
    const float* cond_emb = (const float*)d_in[11];
    const float* gate_W   = (const float*)d_in[12];
    const float* gate_b   = (const float*)d_in[13];
    float* out = (float*)d_out;

    char* ws = (char*)d_ws;
    size_t off = 0;
    const size_t HD = (size_t)Hm * Dm;

    __bf16* xb  = (__bf16*)(ws + off); off = align256(off + (size_t)NTOK * Dm * 2);
    __bf16* W1t = (__bf16*)(ws + off); off = align256(off + (size_t)NBANK * HD * 2);
    __bf16* W2t = (__bf16*)(ws + off); off = align256(off + (size_t)NBANK * HD * 2);
    __bf16* hb  = (__bf16*)(ws + off); off = align256(off + (size_t)NTOK * Em * Hm * 2);
    __bf16* eo  = (__bf16*)(ws + off); off = align256(off + (size_t)NTOK * Em * Dm * 2);
    int*    gids   = (int*)(ws + off); off = align256(off + (size_t)NTOK * 4);
    int*    counts = (int*)(ws + off); off = align256(off + 256);
    int*    lists  = (int*)(ws + off); off = align256(off + (size_t)NGm * NTOK * 4);
    int2*   table  = (int2*)(ws + off); off = align256(off + (size_t)MAXMT * 8);
    int*    ntot   = (int*)(ws + off);  off = align256(off + 256);
    (void)ws_size; (void)n_in; (void)in_sizes; (void)out_size;

    // 1) setup: bucket+table | x cvt | weight transposes (one dispatch)
    k_setup<<<1 + CVT_BLKS + TRANS_BLKS, 256, 0, stream>>>(
        x, ids, e2g, Ws1, Wg1, Ws2, Wg2,
        gids, counts, lists, table, ntot, xb, W1t, W2t);

    // 2) FFN layer 1: x @ W1t -> relu -> hb (bf16)
    k_ffn<Dm, Hm, true><<<(Hm / 128) * MT2, 256, 0, stream>>>(
        xb, Dm, 0, W1t, bs1, bg1, counts, lists, table, ntot,
        hb, Em * Hm, Hm);

    // 3) FFN layer 2: hb @ W2t -> eo (bf16)
    k_ffn<Hm, Dm, false><<<(Dm / 128) * MT2, 256, 0, stream>>>(
        hb, Em * Hm, Hm, W2t, bs2, bg2, counts, lists, table, ntot,
        eo, Em * Dm, Dm);

    // 4) fused gate + combine
    k_gc<<<NTOK / 4, 256, 0, stream>>>(x, cond_emb, gids, gate_W, gate_b, eo, out);
}